// Round 2
// baseline (2036.050 us; speedup 1.0000x reference)
//
#include <hip/hip_runtime.h>
#include <cstdint>
#include <cstddef>

#define XLD 161   // x row stride = NFEAT + EXTRA + 1

// ============================ CSR build ============================
__global__ void hist_kernel(const int* __restrict__ row, int* __restrict__ cnt, int E) {
    for (int e = blockIdx.x * blockDim.x + threadIdx.x; e < E; e += gridDim.x * blockDim.x)
        atomicAdd(&cnt[row[e]], 1);
}

// block-local exclusive scan (256/block) + block sums
__global__ __launch_bounds__(256)
void scan1_kernel(const int* __restrict__ cnt, int* __restrict__ offs,
                  int* __restrict__ bsums, int n) {
    int t = threadIdx.x;
    int gid = blockIdx.x * 256 + t;
    int v = (gid < n) ? cnt[gid] : 0;
    int x = v;
#pragma unroll
    for (int o = 1; o < 64; o <<= 1) { int y = __shfl_up(x, o); if ((t & 63) >= o) x += y; }
    __shared__ int ws[4];
    if ((t & 63) == 63) ws[t >> 6] = x;
    __syncthreads();
    int add = 0;
    for (int w = 0; w < (t >> 6); w++) add += ws[w];
    int incl = x + add;
    if (gid < n) offs[gid] = incl - v;
    if (t == 255) bsums[blockIdx.x] = incl;
}

// exclusive scan of block sums (nb <= 256), in place
__global__ __launch_bounds__(256)
void scan2_kernel(int* __restrict__ bsums, int nb) {
    int t = threadIdx.x;
    int v = (t < nb) ? bsums[t] : 0;
    int x = v;
#pragma unroll
    for (int o = 1; o < 64; o <<= 1) { int y = __shfl_up(x, o); if ((t & 63) >= o) x += y; }
    __shared__ int ws[4];
    if ((t & 63) == 63) ws[t >> 6] = x;
    __syncthreads();
    int add = 0;
    for (int w = 0; w < (t >> 6); w++) add += ws[w];
    if (t < nb) bsums[t] = x + add - v;
}

__global__ void scan3_kernel(int* __restrict__ offs, int* __restrict__ cursor,
                             const int* __restrict__ bsums, int n, int E) {
    int gid = blockIdx.x * 256 + threadIdx.x;
    if (gid < n) {
        int o = offs[gid] + bsums[blockIdx.x];
        offs[gid] = o;
        cursor[gid] = o;
    }
    if (gid == 0) offs[n] = E;
}

__global__ void scatter_kernel(const int* __restrict__ row, const int* __restrict__ col,
                               const float* __restrict__ val, int* __restrict__ cursor,
                               int* __restrict__ colA, float* __restrict__ valA, int E) {
    for (int e = blockIdx.x * blockDim.x + threadIdx.x; e < E; e += gridDim.x * blockDim.x) {
        int r = row[e];
        int p = atomicAdd(&cursor[r], 1);
        colA[p] = col[e];
        valA[p] = val[e];
    }
}

// ============================ GEMM: row-per-lane, W via scalar loads (zero LDS) ============================
// Out[n x C] = H[n x K] @ W[K x C] (+bias, relu). Each 64-lane wave: 64 rows x 32 cols.
// H element k read from A1 if k < split else A2 at (k - split).
template <int K, int C>
__global__ __launch_bounds__(64 * (C / 32))
void gemm_rs(const float* __restrict__ A1, int ld1, int split,
             const float* __restrict__ A2, int ld2,
             const float* __restrict__ W, const float* __restrict__ bias, int doRelu,
             float* __restrict__ Out, int n) {
    constexpr int CW = 32;
    int lane  = threadIdx.x & 63;
    int cbase = __builtin_amdgcn_readfirstlane((threadIdx.x >> 6) * CW);
    int r  = blockIdx.x * 64 + lane;
    int rr = (r < n) ? r : (n - 1);
    const float* __restrict__ a1 = A1 + (size_t)rr * ld1;
    const float* __restrict__ a2 = A2 + (size_t)rr * ld2;
    float acc[CW];
#pragma unroll
    for (int c = 0; c < CW; c++) acc[c] = 0.f;

#pragma unroll 4
    for (int k = 0; k < K; k += 2) {
        const float* p0 = (k < split)     ? (a1 + k)           : (a2 + (k - split));
        const float* p1 = (k + 1 < split) ? (a1 + k + 1)       : (a2 + (k + 1 - split));
        float h0 = *p0;
        float h1 = *p1;
        const float* w0 = W + (size_t)k * C + cbase;
#pragma unroll
        for (int c = 0; c < CW; c++) acc[c] = fmaf(h0, w0[c], acc[c]);
#pragma unroll
        for (int c = 0; c < CW; c++) acc[c] = fmaf(h1, w0[C + c], acc[c]);
    }

    if (r < n) {
        float* o = Out + (size_t)r * C + cbase;
#pragma unroll
        for (int c = 0; c < CW; c++) {
            float v = acc[c];
            if (bias) v += bias[cbase + c];
            if (doRelu) v = fmaxf(v, 0.f);
            o[c] = v;
        }
    }
}

// ============================ Aggregation: one wave per node ============================
// Halves of the wave take even/odd edges (4 pairs unrolled -> 12 gathers in flight);
// combine via shfl; epilogue (+cb*vsum + bias, relu) + BN-stats block reduce.
template <int C, bool DOBN>
__global__ __launch_bounds__(256)
void agg_kernel(const float* __restrict__ S, const int* __restrict__ offs,
                const int* __restrict__ colA, const float* __restrict__ valA,
                const float* __restrict__ cb, const float* __restrict__ bias,
                float* __restrict__ Hout, float* __restrict__ bsum,
                float* __restrict__ bsumsq, int n) {
    constexpr int NA = C / 32;
    int wv   = threadIdx.x >> 6;   // wave id in block (4 waves = 4 nodes)
    int lane = threadIdx.x & 63;
    int half = lane >> 5;          // 0/1 -> even/odd edges
    int f    = lane & 31;          // feature base
    int node = blockIdx.x * 4 + wv;

    float psum[NA], psq[NA];
#pragma unroll
    for (int a = 0; a < NA; a++) { psum[a] = 0.f; psq[a] = 0.f; }

    if (node < n) {
        int e0 = offs[node], e1 = offs[node + 1];
        float acc[NA];
#pragma unroll
        for (int a = 0; a < NA; a++) acc[a] = 0.f;
        float vsum = 0.f;

        int eBase = e0;
        for (; eBase + 8 <= e1; eBase += 8) {
            int ee = eBase + half;
#pragma unroll
            for (int j = 0; j < 4; j++) {
                int idx = ee + 2 * j;
                int   c = colA[idx];
                float v = valA[idx];
                const float* srow = S + (size_t)c * C;
#pragma unroll
                for (int a = 0; a < NA; a++) acc[a] = fmaf(v, srow[f + 32 * a], acc[a]);
                vsum += v;
            }
        }
        for (int ee = eBase + half; ee < e1; ee += 2) {
            int   c = colA[ee];
            float v = valA[ee];
            const float* srow = S + (size_t)c * C;
#pragma unroll
            for (int a = 0; a < NA; a++) acc[a] = fmaf(v, srow[f + 32 * a], acc[a]);
            vsum += v;
        }

        // combine halves (whole wave active -> shfl safe)
#pragma unroll
        for (int a = 0; a < NA; a++) acc[a] += __shfl_down(acc[a], 32);
        vsum += __shfl_down(vsum, 32);

        if (half == 0) {
#pragma unroll
            for (int a = 0; a < NA; a++) {
                int cc = f + 32 * a;
                float o = acc[a] + cb[cc] * vsum + bias[cc];
                o = fmaxf(o, 0.f);
                Hout[(size_t)node * C + cc] = o;
                if (DOBN) { psum[a] = o; psq[a] = o * o; }
            }
        }
    }

    if (DOBN) {
        __shared__ float red[4 * C];
        if (half == 0) {
#pragma unroll
            for (int a = 0; a < NA; a++) red[wv * C + f + 32 * a] = psum[a];
        }
        __syncthreads();
        if (threadIdx.x < C) {
            float s = red[threadIdx.x] + red[C + threadIdx.x] +
                      red[2 * C + threadIdx.x] + red[3 * C + threadIdx.x];
            atomicAdd(&bsum[threadIdx.x], s);
        }
        __syncthreads();
        if (half == 0) {
#pragma unroll
            for (int a = 0; a < NA; a++) red[wv * C + f + 32 * a] = psq[a];
        }
        __syncthreads();
        if (threadIdx.x < C) {
            float s = red[threadIdx.x] + red[C + threadIdx.x] +
                      red[2 * C + threadIdx.x] + red[3 * C + threadIdx.x];
            atomicAdd(&bsumsq[threadIdx.x], s);
        }
    }
}

// ============================ BN fold: Wf = inv*W, cb = -sum(mean*inv*W) ============================
template <int C>
__global__ __launch_bounds__(256)
void fold_kernel(const float* __restrict__ W, float* __restrict__ bsum,
                 float* __restrict__ bsumsq, float* __restrict__ Wf,
                 float* __restrict__ cb, int N) {
    __shared__ float mean[96], inv[96];
    int t = threadIdx.x;
    float rn = 1.0f / (float)N;
    if (t < 96) {
        float mu  = bsum[t] * rn;
        float var = bsumsq[t] * rn - mu * mu;
        mean[t] = mu;
        inv[t]  = rsqrtf(var + 1e-5f);
        bsum[t] = 0.f;        // re-zero for next layer's accumulation
        bsumsq[t] = 0.f;
    }
    __syncthreads();
    for (int i = t; i < 96 * C; i += 256) {
        int k = i / C;
        Wf[i] = inv[k] * W[i];
    }
    if (t < C) {
        float s = 0.f;
        for (int k = 0; k < 96; k++) s += mean[k] * inv[k] * W[k * C + t];
        cb[t] = -s;
    }
}

// ============================ final dot (64->1) + global min ============================
__global__ __launch_bounds__(256)
void dot_min_kernel(const float* __restrict__ A, const float* __restrict__ M3w,
                    const float* __restrict__ M3b, float* __restrict__ m,
                    unsigned* __restrict__ gmin, int n) {
    int lane = threadIdx.x & 63;
    int wv   = threadIdx.x >> 6;
    float w  = M3w[lane];
    float b  = M3b[0];
    float lmin = 3.4e38f;
    int nw = gridDim.x * 4;
    for (int r = blockIdx.x * 4 + wv; r < n; r += nw) {
        float v = A[(size_t)r * 64 + lane] * w;
#pragma unroll
        for (int o = 32; o; o >>= 1) v += __shfl_down(v, o);
        if (lane == 0) {
            float mv = v + b;
            m[r] = mv;
            lmin = fminf(lmin, mv);
        }
    }
#pragma unroll
    for (int o = 32; o; o >>= 1) lmin = fminf(lmin, __shfl_down(lmin, o));
    __shared__ float sm[4];
    if (lane == 0) sm[wv] = lmin;
    __syncthreads();
    if (threadIdx.x == 0) {
        float mn = fminf(fminf(sm[0], sm[1]), fminf(sm[2], sm[3]));
        unsigned u = __float_as_uint(mn);
        unsigned key = (u >> 31) ? ~u : (u | 0x80000000u);
        atomicMin(gmin, key);
    }
}

__global__ void where_kernel(const float* __restrict__ x, float* __restrict__ m,
                             const unsigned* __restrict__ gmin, int n) {
    int i = blockIdx.x * blockDim.x + threadIdx.x;
    if (i < n) {
        unsigned k = *gmin;
        unsigned u = (k >> 31) ? (k ^ 0x80000000u) : ~k;
        float g = __uint_as_float(u);
        if (x[(size_t)i * XLD + 160] == 0.0f) m[i] = g;
    }
}

// ============================ exact radix select: (kwant)-th largest ============================
__device__ inline unsigned fkey(float f) {
    unsigned u = __float_as_uint(f);
    return (u >> 31) ? ~u : (u | 0x80000000u);
}

__global__ __launch_bounds__(1024)
void select_kernel(const float* __restrict__ m, int n, int kwant, float* __restrict__ thresh) {
    __shared__ unsigned hist[256];
    __shared__ unsigned sprefix;
    __shared__ int skk;
    int t = threadIdx.x;
    if (t == 0) { sprefix = 0u; skk = kwant; }
    for (int pass = 0; pass < 4; ++pass) {
        if (t < 256) hist[t] = 0u;
        __syncthreads();
        int shift = 24 - 8 * pass;
        unsigned pfx = sprefix;
        for (int i = t; i < n; i += 1024) {
            unsigned key = fkey(m[i]);
            bool ok = (pass == 0) || ((key >> (shift + 8)) == (pfx >> (shift + 8)));
            if (ok) atomicAdd(&hist[(key >> shift) & 255u], 1u);
        }
        __syncthreads();
        if (t == 0) {
            int cum = 0, kk = skk, chosen = 0;
            for (int b = 255; b >= 0; b--) {
                cum += (int)hist[b];
                if (cum >= kk) { chosen = b; kk -= (cum - (int)hist[b]); break; }
            }
            sprefix = pfx | ((unsigned)chosen << shift);
            skk = kk;
        }
        __syncthreads();
    }
    if (t == 0) {
        unsigned key = sprefix;
        unsigned u = (key >> 31) ? (key ^ 0x80000000u) : ~key;
        *thresh = __uint_as_float(u);
    }
}

__global__ void mask_kernel(const float* __restrict__ m, const float* __restrict__ thresh,
                            float* __restrict__ out, int n) {
    int i = blockIdx.x * blockDim.x + threadIdx.x;
    if (i < n) {
        float t = *thresh, v = m[i];
        out[i] = (v > t) ? v * (1.0f / v) : 0.0f;
    }
}

// ============================ launch ============================
extern "C" void kernel_launch(void* const* d_in, const int* in_sizes, int n_in,
                              void* d_out, int out_size, void* d_ws, size_t ws_size,
                              hipStream_t stream) {
    const float* x   = (const float*)d_in[0];
    const int*   row = (const int*)d_in[1];
    const int*   col = (const int*)d_in[2];
    const float* val = (const float*)d_in[3];
    const float* W1  = (const float*)d_in[4];
    const float* b1  = (const float*)d_in[5];
    const float* W2  = (const float*)d_in[6];
    const float* b2  = (const float*)d_in[7];
    const float* W3  = (const float*)d_in[8];
    const float* b3  = (const float*)d_in[9];
    const float* W4  = (const float*)d_in[10];
    const float* b4  = (const float*)d_in[11];
    const float* W5  = (const float*)d_in[12];
    const float* b5  = (const float*)d_in[13];
    const float* M1w = (const float*)d_in[14];
    const float* M1b = (const float*)d_in[15];
    const float* M2w = (const float*)d_in[16];
    const float* M2b = (const float*)d_in[17];
    const float* M3w = (const float*)d_in[18];
    const float* M3b = (const float*)d_in[19];

    const int n = in_sizes[0] / XLD;   // 50000
    const int E = in_sizes[1];         // 800000

    char* ws = (char*)d_ws;
    size_t off = 0;
    auto carve = [&](size_t bytes) -> void* {
        void* p = ws + off;
        off = (off + bytes + 255) & ~(size_t)255;
        return p;
    };
    int*      offs   = (int*)carve((size_t)(n + 1) * 4);
    int*      cursor = (int*)carve((size_t)n * 4);        // histogram, then scatter cursor
    int*      bsums  = (int*)carve(256 * 4);
    int*      colA   = (int*)carve((size_t)E * 4);
    float*    valA   = (float*)carve((size_t)E * 4);
    float*    h      = (float*)carve((size_t)n * 96 * 4); // activations (h5 = first n*64)
    float*    big    = (float*)carve((size_t)n * 128 * 4);// s buffer (n*96) / a1 (n*128)
    float*    Wf     = (float*)carve(96 * 96 * 4);
    float*    stats  = (float*)carve(288 * 4);            // cb0 | bsum | bsumsq
    float*    cb     = (float*)carve(96 * 4);
    float*    m      = (float*)carve((size_t)n * 4);
    unsigned* gmin   = (unsigned*)carve(4);
    float*    thresh = (float*)carve(4);
    float* cb0    = stats;
    float* bsum   = stats + 96;
    float* bsumsq = stats + 192;

    hipMemsetAsync(cursor, 0, (size_t)n * 4, stream);
    hipMemsetAsync(stats, 0, 288 * 4, stream);
    hipMemsetAsync(gmin, 0xFF, 4, stream);

    // CSR build
    const int nb = (n + 255) / 256;
    hist_kernel<<<512, 256, 0, stream>>>(row, cursor, E);
    scan1_kernel<<<nb, 256, 0, stream>>>(cursor, offs, bsums, n);
    scan2_kernel<<<1, 256, 0, stream>>>(bsums, nb);
    scan3_kernel<<<nb, 256, 0, stream>>>(offs, cursor, bsums, n, E);
    scatter_kernel<<<512, 256, 0, stream>>>(row, col, val, cursor, colA, valA, E);

    const int gg = (n + 63) / 64;       // 782 row-tiles
    const int ga = (n + 3) / 4;         // 12500 agg blocks

    // Layer 1
    gemm_rs<128, 96><<<gg, 192, 0, stream>>>(x, XLD, 128, x, XLD, W1, nullptr, 0, big, n);
    agg_kernel<96, true><<<ga, 256, 0, stream>>>(big, offs, colA, valA, cb0, b1, h, bsum, bsumsq, n);

    // Layers 2-4
    fold_kernel<96><<<1, 256, 0, stream>>>(W2, bsum, bsumsq, Wf, cb, n);
    gemm_rs<96, 96><<<gg, 192, 0, stream>>>(h, 96, 96, h, 96, Wf, nullptr, 0, big, n);
    agg_kernel<96, true><<<ga, 256, 0, stream>>>(big, offs, colA, valA, cb, b2, h, bsum, bsumsq, n);

    fold_kernel<96><<<1, 256, 0, stream>>>(W3, bsum, bsumsq, Wf, cb, n);
    gemm_rs<96, 96><<<gg, 192, 0, stream>>>(h, 96, 96, h, 96, Wf, nullptr, 0, big, n);
    agg_kernel<96, true><<<ga, 256, 0, stream>>>(big, offs, colA, valA, cb, b3, h, bsum, bsumsq, n);

    fold_kernel<96><<<1, 256, 0, stream>>>(W4, bsum, bsumsq, Wf, cb, n);
    gemm_rs<96, 96><<<gg, 192, 0, stream>>>(h, 96, 96, h, 96, Wf, nullptr, 0, big, n);
    agg_kernel<96, true><<<ga, 256, 0, stream>>>(big, offs, colA, valA, cb, b4, h, bsum, bsumsq, n);

    // Layer 5 (96 -> 64, no BN after)
    fold_kernel<64><<<1, 256, 0, stream>>>(W5, bsum, bsumsq, Wf, cb, n);
    gemm_rs<96, 64><<<gg, 128, 0, stream>>>(h, 96, 96, h, 96, Wf, nullptr, 0, big, n);
    agg_kernel<64, false><<<ga, 256, 0, stream>>>(big, offs, colA, valA, cb, b5, h, bsum, bsumsq, n);

    // MLP
    gemm_rs<96, 128><<<gg, 256, 0, stream>>>(h, 64, 64, x + 128, XLD, M1w, M1b, 1, big, n);
    gemm_rs<128, 64><<<gg, 128, 0, stream>>>(big, 128, 128, big, 128, M2w, M2b, 1, h, n);

    // m = a2 @ M3w + M3b ; global min
    dot_min_kernel<<<256, 256, 0, stream>>>(h, M3w, M3b, m, gmin, n);

    // where(grp==0, min, m)
    where_kernel<<<(n + 255) / 256, 256, 0, stream>>>(x, m, gmin, n);

    // exact 71st-largest threshold
    select_kernel<<<1, 1024, 0, stream>>>(m, n, 71, thresh);

    // out = m>thresh ? 1 : 0 (as m * (1/m))
    mask_kernel<<<(n + 255) / 256, 256, 0, stream>>>(m, thresh, (float*)d_out, n);
}

// Round 3
// 1138.236 us; speedup vs baseline: 1.7888x; 1.7888x over previous
//
#include <hip/hip_runtime.h>
#include <cstdint>
#include <cstddef>

#define XLD 161   // x row stride = NFEAT + EXTRA + 1

// ============================ CSR build ============================
__global__ void hist_kernel(const int* __restrict__ row, int* __restrict__ cnt, int E) {
    for (int e = blockIdx.x * blockDim.x + threadIdx.x; e < E; e += gridDim.x * blockDim.x)
        atomicAdd(&cnt[row[e]], 1);
}

// block-local exclusive scan (256/block) + block sums
__global__ __launch_bounds__(256)
void scan1_kernel(const int* __restrict__ cnt, int* __restrict__ offs,
                  int* __restrict__ bsums, int n) {
    int t = threadIdx.x;
    int gid = blockIdx.x * 256 + t;
    int v = (gid < n) ? cnt[gid] : 0;
    int x = v;
#pragma unroll
    for (int o = 1; o < 64; o <<= 1) { int y = __shfl_up(x, o); if ((t & 63) >= o) x += y; }
    __shared__ int ws[4];
    if ((t & 63) == 63) ws[t >> 6] = x;
    __syncthreads();
    int add = 0;
    for (int w = 0; w < (t >> 6); w++) add += ws[w];
    int incl = x + add;
    if (gid < n) offs[gid] = incl - v;
    if (t == 255) bsums[blockIdx.x] = incl;
}

// exclusive scan of block sums (nb <= 256), in place
__global__ __launch_bounds__(256)
void scan2_kernel(int* __restrict__ bsums, int nb) {
    int t = threadIdx.x;
    int v = (t < nb) ? bsums[t] : 0;
    int x = v;
#pragma unroll
    for (int o = 1; o < 64; o <<= 1) { int y = __shfl_up(x, o); if ((t & 63) >= o) x += y; }
    __shared__ int ws[4];
    if ((t & 63) == 63) ws[t >> 6] = x;
    __syncthreads();
    int add = 0;
    for (int w = 0; w < (t >> 6); w++) add += ws[w];
    if (t < nb) bsums[t] = x + add - v;
}

__global__ void scan3_kernel(int* __restrict__ offs, int* __restrict__ cursor,
                             const int* __restrict__ bsums, int n, int E) {
    int gid = blockIdx.x * 256 + threadIdx.x;
    if (gid < n) {
        int o = offs[gid] + bsums[blockIdx.x];
        offs[gid] = o;
        cursor[gid] = o;
    }
    if (gid == 0) offs[n] = E;
}

__global__ void scatter_kernel(const int* __restrict__ row, const int* __restrict__ col,
                               const float* __restrict__ val, int* __restrict__ cursor,
                               int* __restrict__ colA, float* __restrict__ valA, int E) {
    for (int e = blockIdx.x * blockDim.x + threadIdx.x; e < E; e += gridDim.x * blockDim.x) {
        int r = row[e];
        int p = atomicAdd(&cursor[r], 1);
        colA[p] = col[e];
        valA[p] = val[e];
    }
}

// ============================ GEMM: row-per-lane, W via scalar loads (zero LDS) ============================
// Out[n x C] = H[n x K] @ W[K x C] (+bias, relu). Each 64-lane wave: 64 rows x 32 cols.
// H element k read from A1 if k < split else A2 at (k - split).
template <int K, int C>
__global__ __launch_bounds__(64 * (C / 32))
void gemm_rs(const float* __restrict__ A1, int ld1, int split,
             const float* __restrict__ A2, int ld2,
             const float* __restrict__ W, const float* __restrict__ bias, int doRelu,
             float* __restrict__ Out, int n) {
    constexpr int CW = 32;
    int lane  = threadIdx.x & 63;
    int cbase = __builtin_amdgcn_readfirstlane((threadIdx.x >> 6) * CW);
    int r  = blockIdx.x * 64 + lane;
    int rr = (r < n) ? r : (n - 1);
    const float* __restrict__ a1 = A1 + (size_t)rr * ld1;
    const float* __restrict__ a2 = A2 + (size_t)rr * ld2;
    float acc[CW];
#pragma unroll
    for (int c = 0; c < CW; c++) acc[c] = 0.f;

#pragma unroll 4
    for (int k = 0; k < K; k += 2) {
        const float* p0 = (k < split)     ? (a1 + k)           : (a2 + (k - split));
        const float* p1 = (k + 1 < split) ? (a1 + k + 1)       : (a2 + (k + 1 - split));
        float h0 = *p0;
        float h1 = *p1;
        const float* w0 = W + (size_t)k * C + cbase;
#pragma unroll
        for (int c = 0; c < CW; c++) acc[c] = fmaf(h0, w0[c], acc[c]);
#pragma unroll
        for (int c = 0; c < CW; c++) acc[c] = fmaf(h1, w0[C + c], acc[c]);
    }

    if (r < n) {
        float* o = Out + (size_t)r * C + cbase;
#pragma unroll
        for (int c = 0; c < CW; c++) {
            float v = acc[c];
            if (bias) v += bias[cbase + c];
            if (doRelu) v = fmaxf(v, 0.f);
            o[c] = v;
        }
    }
}

// ============================ Aggregation (CSR SpMM) + bias + relu + BN stats ============================
// 32-lane group per node, 8 groups/block, grid-stride; edge loop unrolled x4 with
// 4 independent accumulator sets (4 gather chains in flight per group).
// BN stats accumulated in registers across the group's nodes; one LDS reduce +
// one atomic burst per block at the end.
template <int C, bool DOBN>
__global__ __launch_bounds__(256)
void agg_kernel(const float* __restrict__ S, const int* __restrict__ offs,
                const int* __restrict__ colA, const float* __restrict__ valA,
                const float* __restrict__ cb, const float* __restrict__ bias,
                float* __restrict__ Hout, float* __restrict__ bsum,
                float* __restrict__ bsumsq, int n) {
    constexpr int NA = C / 32;
    int lane = threadIdx.x & 31;
    int grp  = threadIdx.x >> 5;   // 8 groups of 32 lanes
    float psum[NA], psq[NA];
#pragma unroll
    for (int a = 0; a < NA; a++) { psum[a] = 0.f; psq[a] = 0.f; }

    for (int node = blockIdx.x * 8 + grp; node < n; node += gridDim.x * 8) {
        int e0 = offs[node], e1 = offs[node + 1];
        float x0[NA], x1[NA], x2[NA], x3[NA];
#pragma unroll
        for (int a = 0; a < NA; a++) { x0[a] = 0.f; x1[a] = 0.f; x2[a] = 0.f; x3[a] = 0.f; }
        float vs0 = 0.f, vs1 = 0.f, vs2 = 0.f, vs3 = 0.f;

        int e = e0;
        for (; e + 4 <= e1; e += 4) {
            int   c0 = colA[e],     c1 = colA[e + 1], c2 = colA[e + 2], c3 = colA[e + 3];
            float v0 = valA[e],     v1 = valA[e + 1], v2 = valA[e + 2], v3 = valA[e + 3];
            const float* s0 = S + (size_t)c0 * C;
            const float* s1 = S + (size_t)c1 * C;
            const float* s2 = S + (size_t)c2 * C;
            const float* s3 = S + (size_t)c3 * C;
#pragma unroll
            for (int a = 0; a < NA; a++) {
                int ff = lane + 32 * a;
                x0[a] = fmaf(v0, s0[ff], x0[a]);
                x1[a] = fmaf(v1, s1[ff], x1[a]);
                x2[a] = fmaf(v2, s2[ff], x2[a]);
                x3[a] = fmaf(v3, s3[ff], x3[a]);
            }
            vs0 += v0; vs1 += v1; vs2 += v2; vs3 += v3;
        }
        for (; e < e1; e++) {
            int   c = colA[e];
            float v = valA[e];
            const float* s0 = S + (size_t)c * C;
#pragma unroll
            for (int a = 0; a < NA; a++) x0[a] = fmaf(v, s0[lane + 32 * a], x0[a]);
            vs0 += v;
        }
        float vsum = (vs0 + vs1) + (vs2 + vs3);
#pragma unroll
        for (int a = 0; a < NA; a++) {
            int cc = lane + 32 * a;
            float o = ((x0[a] + x1[a]) + (x2[a] + x3[a])) + cb[cc] * vsum + bias[cc];
            o = fmaxf(o, 0.f);
            Hout[(size_t)node * C + cc] = o;
            if (DOBN) { psum[a] += o; psq[a] += o * o; }
        }
    }

    if (DOBN) {
        __shared__ float red[DOBN ? 8 * C : 1];
#pragma unroll
        for (int a = 0; a < NA; a++) red[grp * C + lane + 32 * a] = psum[a];
        __syncthreads();
        if (threadIdx.x < C) {
            float s = 0.f;
            for (int g = 0; g < 8; g++) s += red[g * C + threadIdx.x];
            atomicAdd(&bsum[threadIdx.x], s);
        }
        __syncthreads();
#pragma unroll
        for (int a = 0; a < NA; a++) red[grp * C + lane + 32 * a] = psq[a];
        __syncthreads();
        if (threadIdx.x < C) {
            float s = 0.f;
            for (int g = 0; g < 8; g++) s += red[g * C + threadIdx.x];
            atomicAdd(&bsumsq[threadIdx.x], s);
        }
    }
}

// ============================ BN fold: Wf = inv*W, cb = -sum(mean*inv*W) ============================
template <int C>
__global__ __launch_bounds__(256)
void fold_kernel(const float* __restrict__ W, float* __restrict__ bsum,
                 float* __restrict__ bsumsq, float* __restrict__ Wf,
                 float* __restrict__ cb, int N) {
    __shared__ float mean[96], inv[96];
    int t = threadIdx.x;
    float rn = 1.0f / (float)N;
    if (t < 96) {
        float mu  = bsum[t] * rn;
        float var = bsumsq[t] * rn - mu * mu;
        mean[t] = mu;
        inv[t]  = rsqrtf(var + 1e-5f);
        bsum[t] = 0.f;        // re-zero for next layer's accumulation
        bsumsq[t] = 0.f;
    }
    __syncthreads();
    for (int i = t; i < 96 * C; i += 256) {
        int k = i / C;
        Wf[i] = inv[k] * W[i];
    }
    if (t < C) {
        float s = 0.f;
        for (int k = 0; k < 96; k++) s += mean[k] * inv[k] * W[k * C + t];
        cb[t] = -s;
    }
}

// ============================ final dot (64->1) + global min ============================
__global__ __launch_bounds__(256)
void dot_min_kernel(const float* __restrict__ A, const float* __restrict__ M3w,
                    const float* __restrict__ M3b, float* __restrict__ m,
                    unsigned* __restrict__ gmin, int n) {
    int lane = threadIdx.x & 63;
    int wv   = threadIdx.x >> 6;
    float w  = M3w[lane];
    float b  = M3b[0];
    float lmin = 3.4e38f;
    int nw = gridDim.x * 4;
    for (int r = blockIdx.x * 4 + wv; r < n; r += nw) {
        float v = A[(size_t)r * 64 + lane] * w;
#pragma unroll
        for (int o = 32; o; o >>= 1) v += __shfl_down(v, o);
        if (lane == 0) {
            float mv = v + b;
            m[r] = mv;
            lmin = fminf(lmin, mv);
        }
    }
#pragma unroll
    for (int o = 32; o; o >>= 1) lmin = fminf(lmin, __shfl_down(lmin, o));
    __shared__ float sm[4];
    if (lane == 0) sm[wv] = lmin;
    __syncthreads();
    if (threadIdx.x == 0) {
        float mn = fminf(fminf(sm[0], sm[1]), fminf(sm[2], sm[3]));
        unsigned u = __float_as_uint(mn);
        unsigned key = (u >> 31) ? ~u : (u | 0x80000000u);
        atomicMin(gmin, key);
    }
}

__global__ void where_kernel(const float* __restrict__ x, float* __restrict__ m,
                             const unsigned* __restrict__ gmin, int n) {
    int i = blockIdx.x * blockDim.x + threadIdx.x;
    if (i < n) {
        unsigned k = *gmin;
        unsigned u = (k >> 31) ? (k ^ 0x80000000u) : ~k;
        float g = __uint_as_float(u);
        if (x[(size_t)i * XLD + 160] == 0.0f) m[i] = g;
    }
}

// ============================ exact radix select: (kwant)-th largest ============================
__device__ inline unsigned fkey(float f) {
    unsigned u = __float_as_uint(f);
    return (u >> 31) ? ~u : (u | 0x80000000u);
}

__global__ __launch_bounds__(1024)
void select_kernel(const float* __restrict__ m, int n, int kwant, float* __restrict__ thresh) {
    __shared__ unsigned hist[256];
    __shared__ unsigned sprefix;
    __shared__ int skk;
    int t = threadIdx.x;
    if (t == 0) { sprefix = 0u; skk = kwant; }
    for (int pass = 0; pass < 4; ++pass) {
        if (t < 256) hist[t] = 0u;
        __syncthreads();
        int shift = 24 - 8 * pass;
        unsigned pfx = sprefix;
        for (int i = t; i < n; i += 1024) {
            unsigned key = fkey(m[i]);
            bool ok = (pass == 0) || ((key >> (shift + 8)) == (pfx >> (shift + 8)));
            if (ok) atomicAdd(&hist[(key >> shift) & 255u], 1u);
        }
        __syncthreads();
        if (t == 0) {
            int cum = 0, kk = skk, chosen = 0;
            for (int b = 255; b >= 0; b--) {
                cum += (int)hist[b];
                if (cum >= kk) { chosen = b; kk -= (cum - (int)hist[b]); break; }
            }
            sprefix = pfx | ((unsigned)chosen << shift);
            skk = kk;
        }
        __syncthreads();
    }
    if (t == 0) {
        unsigned key = sprefix;
        unsigned u = (key >> 31) ? (key ^ 0x80000000u) : ~key;
        *thresh = __uint_as_float(u);
    }
}

__global__ void mask_kernel(const float* __restrict__ m, const float* __restrict__ thresh,
                            float* __restrict__ out, int n) {
    int i = blockIdx.x * blockDim.x + threadIdx.x;
    if (i < n) {
        float t = *thresh, v = m[i];
        out[i] = (v > t) ? v * (1.0f / v) : 0.0f;
    }
}

// ============================ launch ============================
extern "C" void kernel_launch(void* const* d_in, const int* in_sizes, int n_in,
                              void* d_out, int out_size, void* d_ws, size_t ws_size,
                              hipStream_t stream) {
    const float* x   = (const float*)d_in[0];
    const int*   row = (const int*)d_in[1];
    const int*   col = (const int*)d_in[2];
    const float* val = (const float*)d_in[3];
    const float* W1  = (const float*)d_in[4];
    const float* b1  = (const float*)d_in[5];
    const float* W2  = (const float*)d_in[6];
    const float* b2  = (const float*)d_in[7];
    const float* W3  = (const float*)d_in[8];
    const float* b3  = (const float*)d_in[9];
    const float* W4  = (const float*)d_in[10];
    const float* b4  = (const float*)d_in[11];
    const float* W5  = (const float*)d_in[12];
    const float* b5  = (const float*)d_in[13];
    const float* M1w = (const float*)d_in[14];
    const float* M1b = (const float*)d_in[15];
    const float* M2w = (const float*)d_in[16];
    const float* M2b = (const float*)d_in[17];
    const float* M3w = (const float*)d_in[18];
    const float* M3b = (const float*)d_in[19];

    const int n = in_sizes[0] / XLD;   // 50000
    const int E = in_sizes[1];         // 800000

    char* ws = (char*)d_ws;
    size_t off = 0;
    auto carve = [&](size_t bytes) -> void* {
        void* p = ws + off;
        off = (off + bytes + 255) & ~(size_t)255;
        return p;
    };
    int*      offs   = (int*)carve((size_t)(n + 1) * 4);
    int*      cursor = (int*)carve((size_t)n * 4);        // histogram, then scatter cursor
    int*      bsums  = (int*)carve(256 * 4);
    int*      colA   = (int*)carve((size_t)E * 4);
    float*    valA   = (float*)carve((size_t)E * 4);
    float*    h      = (float*)carve((size_t)n * 96 * 4); // activations (h5 = first n*64)
    float*    big    = (float*)carve((size_t)n * 128 * 4);// s buffer (n*96) / a1 (n*128)
    float*    Wf     = (float*)carve(96 * 96 * 4);
    float*    stats  = (float*)carve(288 * 4);            // cb0 | bsum | bsumsq
    float*    cb     = (float*)carve(96 * 4);
    float*    m      = (float*)carve((size_t)n * 4);
    unsigned* gmin   = (unsigned*)carve(4);
    float*    thresh = (float*)carve(4);
    float* cb0    = stats;
    float* bsum   = stats + 96;
    float* bsumsq = stats + 192;

    hipMemsetAsync(cursor, 0, (size_t)n * 4, stream);
    hipMemsetAsync(stats, 0, 288 * 4, stream);
    hipMemsetAsync(gmin, 0xFF, 4, stream);

    // CSR build
    const int nb = (n + 255) / 256;
    hist_kernel<<<512, 256, 0, stream>>>(row, cursor, E);
    scan1_kernel<<<nb, 256, 0, stream>>>(cursor, offs, bsums, n);
    scan2_kernel<<<1, 256, 0, stream>>>(bsums, nb);
    scan3_kernel<<<nb, 256, 0, stream>>>(offs, cursor, bsums, n, E);
    scatter_kernel<<<512, 256, 0, stream>>>(row, col, val, cursor, colA, valA, E);

    const int gg = (n + 63) / 64;       // 782 row-tiles
    const int ga = 2048;                // 8 blocks/CU; grid-stride over nodes

    // Layer 1
    gemm_rs<128, 96><<<gg, 192, 0, stream>>>(x, XLD, 128, x, XLD, W1, nullptr, 0, big, n);
    agg_kernel<96, true><<<ga, 256, 0, stream>>>(big, offs, colA, valA, cb0, b1, h, bsum, bsumsq, n);

    // Layers 2-4
    fold_kernel<96><<<1, 256, 0, stream>>>(W2, bsum, bsumsq, Wf, cb, n);
    gemm_rs<96, 96><<<gg, 192, 0, stream>>>(h, 96, 96, h, 96, Wf, nullptr, 0, big, n);
    agg_kernel<96, true><<<ga, 256, 0, stream>>>(big, offs, colA, valA, cb, b2, h, bsum, bsumsq, n);

    fold_kernel<96><<<1, 256, 0, stream>>>(W3, bsum, bsumsq, Wf, cb, n);
    gemm_rs<96, 96><<<gg, 192, 0, stream>>>(h, 96, 96, h, 96, Wf, nullptr, 0, big, n);
    agg_kernel<96, true><<<ga, 256, 0, stream>>>(big, offs, colA, valA, cb, b3, h, bsum, bsumsq, n);

    fold_kernel<96><<<1, 256, 0, stream>>>(W4, bsum, bsumsq, Wf, cb, n);
    gemm_rs<96, 96><<<gg, 192, 0, stream>>>(h, 96, 96, h, 96, Wf, nullptr, 0, big, n);
    agg_kernel<96, true><<<ga, 256, 0, stream>>>(big, offs, colA, valA, cb, b4, h, bsum, bsumsq, n);

    // Layer 5 (96 -> 64, no BN after)
    fold_kernel<64><<<1, 256, 0, stream>>>(W5, bsum, bsumsq, Wf, cb, n);
    gemm_rs<96, 64><<<gg, 128, 0, stream>>>(h, 96, 96, h, 96, Wf, nullptr, 0, big, n);
    agg_kernel<64, false><<<ga, 256, 0, stream>>>(big, offs, colA, valA, cb, b5, h, bsum, bsumsq, n);

    // MLP
    gemm_rs<96, 128><<<gg, 256, 0, stream>>>(h, 64, 64, x + 128, XLD, M1w, M1b, 1, big, n);
    gemm_rs<128, 64><<<gg, 128, 0, stream>>>(big, 128, 128, big, 128, M2w, M2b, 1, h, n);

    // m = a2 @ M3w + M3b ; global min
    dot_min_kernel<<<256, 256, 0, stream>>>(h, M3w, M3b, m, gmin, n);

    // where(grp==0, min, m)
    where_kernel<<<(n + 255) / 256, 256, 0, stream>>>(x, m, gmin, n);

    // exact 71st-largest threshold
    select_kernel<<<1, 1024, 0, stream>>>(m, n, 71, thresh);

    // out = m>thresh ? 1 : 0 (as m * (1/m))
    mask_kernel<<<(n + 255) / 256, 256, 0, stream>>>(m, thresh, (float*)d_out, n);
}